// Round 2
// baseline (12.451 us; speedup 1.0000x reference)
//
#include <hip/hip_runtime.h>
#include <hip/hip_bf16.h>

#define B_    8
#define N_    128
#define NB_   32
#define NORB_ 128
#define RPB   4      // output rows per block
#define THREADS 512

__global__ __launch_bounds__(THREADS) void bobf_kernel(
    const float* __restrict__ chi,
    const float* __restrict__ W,
    float* __restrict__ out)
{
    __shared__ float Sp[16][NB_];            // per-group partial sums for S
    __shared__ float S[NB_];                 // S[k] = sum_j chi[b,j,k]
    __shared__ float x[RPB][NB_];            // the 4 rows' chi values
    __shared__ __align__(16) float p[1024 * RPB];  // p[kl*4 + r]
    __shared__ float red[4][RPB][NORB_];     // cross-quarter reduction

    const int t  = threadIdx.x;
    const int b  = blockIdx.x >> 5;          // 32 blocks per batch
    const int i0 = (blockIdx.x & 31) * RPB;

    // ---- Stage 1: partial sums for S[k]; load the 4 rows' x ----
    {
        const int k = t & 31;
        const int g = t >> 5;                // 0..15, each covers 8 j's
        const float* base = chi + (b * N_) * NB_ + k;
        float s = 0.f;
        #pragma unroll
        for (int jj = 0; jj < 8; ++jj)
            s += base[(g * 8 + jj) * NB_];
        Sp[g][k] = s;
    }
    if (t < RPB * NB_) {
        const int r = t >> 5, l = t & 31;
        x[r][l] = chi[(b * N_ + i0 + r) * NB_ + l];
    }
    __syncthreads();
    if (t < NB_) {
        float s = 0.f;
        #pragma unroll
        for (int g = 0; g < 16; ++g) s += Sp[g][t];
        S[t] = s;
    }
    __syncthreads();

    // ---- Stage 2: p[kl][r] = (S[k]-x[r][k])/127 * x[r][l] ----
    const float inv = 1.0f / (float)(N_ - 1);
    #pragma unroll
    for (int e = 0; e < 8; ++e) {
        const int flat = t + THREADS * e;    // 0..4095
        const int r  = flat & (RPB - 1);
        const int kl = flat >> 2;
        const int k  = kl >> 5, l = kl & 31;
        p[flat] = (S[k] - x[r][k]) * inv * x[r][l];
    }
    __syncthreads();

    // ---- Stage 3: main contraction. thread = (quarter q, orbital o) ----
    const int q = t >> 7;                    // kl in [q*256, q*256+256)
    const int o = t & 127;
    const float* Wp = W + (q * 256) * NORB_ + o;
    const float4* p4 = ((const float4*)p) + q * 256;
    float4 acc = {0.f, 0.f, 0.f, 0.f};
    #pragma unroll 8
    for (int j = 0; j < 256; ++j) {
        const float  w  = Wp[j * NORB_];
        const float4 pv = p4[j];             // broadcast ds_read_b128
        acc.x += pv.x * w;
        acc.y += pv.y * w;
        acc.z += pv.z * w;
        acc.w += pv.w * w;
    }
    red[q][0][o] = acc.x;
    red[q][1][o] = acc.y;
    red[q][2][o] = acc.z;
    red[q][3][o] = acc.w;
    __syncthreads();

    // ---- Stage 4: reduce quarters, store (contiguous 512 floats per block) ----
    {
        const int r = t >> 7;
        const float v = red[0][r][o] + red[1][r][o] + red[2][r][o] + red[3][r][o];
        out[(b * N_ + i0 + r) * NORB_ + o] = v;
    }
}

extern "C" void kernel_launch(void* const* d_in, const int* in_sizes, int n_in,
                              void* d_out, int out_size, void* d_ws, size_t ws_size,
                              hipStream_t stream) {
    const float* chi = (const float*)d_in[0];
    const float* W   = (const float*)d_in[1];
    float* out = (float*)d_out;
    dim3 grid(B_ * (N_ / RPB));   // 256 blocks
    dim3 block(THREADS);
    hipLaunchKernelGGL(bobf_kernel, grid, block, 0, stream, chi, W, out);
}